// Round 1
// baseline (189.593 us; speedup 1.0000x reference)
//
#include <hip/hip_runtime.h>
#include <cstdint>
#include <cstddef>

#define S 8192
#define Dm 1024
#define E 64
#define CAP 128
// out layout (float32 elements):
//   [0]                 l_aux
//   [1 .. 1+S*E*CAP)    combine_weights
//   [1+S*E*CAP .. +2x)  dispatch_mask (0.0/1.0)
//   [1+2*S*E*CAP .. 64) exp_counts (as float)

// ---------------- K1: logits = x @ w^T (fp32) ----------------
// grid 512 = 8 expert-groups x 64 token-tiles; block 128 threads (2 waves).
// Each thread owns one token row, 8 expert accumulators. B (weights) is
// uniform-indexed -> compiler emits s_load (scalar cache), A is per-lane
// sequential float4s (L1 catches the 128B-line reuse across k-chunks).
// blockIdx = et*64 + tt so the 8 expert-split sharers of a token tile are
// 64 apart -> same XCD (bid % 8 equal) -> A reuse hits that XCD's L2.
__global__ __launch_bounds__(128) void k_gemm(const float* __restrict__ x,
                                              const float* __restrict__ w,
                                              float* __restrict__ logits) {
    int bid = blockIdx.x;
    int et = bid >> 6;        // 0..7
    int tt = bid & 63;        // 0..63
    int m = tt * 128 + threadIdx.x;   // token id
    const float* arow = x + (size_t)m * Dm;
    int eb = et * 8;
    float acc[8] = {0.f, 0.f, 0.f, 0.f, 0.f, 0.f, 0.f, 0.f};
    for (int kc = 0; kc < Dm; kc += 8) {
        float4 a0 = *(const float4*)(arow + kc);
        float4 a1 = *(const float4*)(arow + kc + 4);
        float a[8] = {a0.x, a0.y, a0.z, a0.w, a1.x, a1.y, a1.z, a1.w};
#pragma unroll
        for (int kk = 0; kk < 8; ++kk) {
#pragma unroll
            for (int n = 0; n < 8; ++n) {
                acc[n] = fmaf(a[kk], w[(size_t)(eb + n) * Dm + kc + kk], acc[n]);
            }
        }
    }
    float* lrow = logits + (size_t)m * E + eb;
#pragma unroll
    for (int n = 0; n < 8; ++n) lrow[n] = acc[n];
}

// ---------------- K2: per-token softmax/argmax + column sums ----------------
// 128 blocks x 64 threads; tile 64x64 logits in LDS (pad 65: row phase
// conflict-free, col phase 2-way = free).
__global__ __launch_bounds__(64) void k_softmax(const float* __restrict__ logits,
                                                float* __restrict__ gate,
                                                int* __restrict__ idx,
                                                float* __restrict__ me_sum) {
    __shared__ float tile[64][65];
    __shared__ float sm[64];
    __shared__ float sinv[64];
    int t0 = blockIdx.x * 64;
    int tid = threadIdx.x;
    for (int it = 0; it < 16; ++it) {
        int row = it * 4 + (tid >> 4);
        int c4 = (tid & 15) * 4;
        float4 v = *(const float4*)(logits + (size_t)(t0 + row) * E + c4);
        tile[row][c4 + 0] = v.x;
        tile[row][c4 + 1] = v.y;
        tile[row][c4 + 2] = v.z;
        tile[row][c4 + 3] = v.w;
    }
    __syncthreads();
    {   // row phase: max (first-index argmax), exp-sum
        int r = tid;
        float m = tile[r][0];
        int am = 0;
#pragma unroll
        for (int c = 1; c < E; ++c) {
            float v = tile[r][c];
            if (v > m) { m = v; am = c; }   // strict > == first max (jnp.argmax)
        }
        float ssum = 0.f;
#pragma unroll
        for (int c = 0; c < E; ++c) ssum += __expf(tile[r][c] - m);
        float inv = 1.0f / ssum;            // softmax value at argmax
        gate[t0 + r] = inv;
        idx[t0 + r] = am;
        sm[r] = m;
        sinv[r] = inv;
    }
    __syncthreads();
    {   // column phase: per-expert softmax column sums (for me)
        int c = tid;
        float cs = 0.f;
#pragma unroll 8
        for (int r = 0; r < 64; ++r) cs += __expf(tile[r][c] - sm[r]) * sinv[r];
        atomicAdd(&me_sum[c], cs);
    }
}

// ---------------- K3: ordered per-expert scan -> positions, counts, l_aux ----
// 64 blocks (one per expert) x 256 threads; deterministic ballot scan over
// all 8192 tokens in token order.
__global__ __launch_bounds__(256) void k_scan(const int* __restrict__ idx,
                                              int* __restrict__ pos,
                                              const float* __restrict__ me_sum,
                                              float* __restrict__ out_counts,
                                              float* __restrict__ out_laux) {
    int e = blockIdx.x;
    int tid = threadIdx.x;
    int lane = tid & 63;
    int wid = tid >> 6;
    __shared__ int wsum[4];
    int running = 0;   // every thread tracks the same running total
    for (int ch = 0; ch < S / 256; ++ch) {
        int t = ch * 256 + tid;
        bool f = (idx[t] == e);
        unsigned long long b = __ballot(f);
        int pre = __popcll(b & ((1ull << lane) - 1ull));
        if (lane == 0) wsum[wid] = __popcll(b);
        __syncthreads();
        int off = running;
#pragma unroll
        for (int w2 = 0; w2 < 4; ++w2)
            if (w2 < wid) off += wsum[w2];
        if (f) pos[t] = off + pre;     // pre-drop position within expert
        running += wsum[0] + wsum[1] + wsum[2] + wsum[3];
        __syncthreads();
    }
    if (tid == 0) {
        out_counts[e] = (float)running;                       // exp_counts (pre-drop)
        float la = me_sum[e] * (1.0f / (float)S) *
                   ((float)running / (float)S) * (float)E;
        atomicAdd(out_laux, la);                              // l_aux
    }
}

// ---------------- K4: sparse scatter of combine/dispatch ----------------
__global__ __launch_bounds__(256) void k_scatter(const int* __restrict__ idx,
                                                 const int* __restrict__ pos,
                                                 const float* __restrict__ gate,
                                                 float* __restrict__ out) {
    int t = blockIdx.x * 256 + threadIdx.x;
    int p = pos[t];
    if (p < CAP) {
        size_t off = 1 + (size_t)t * (E * CAP) + (size_t)idx[t] * CAP + (size_t)p;
        out[off] = gate[t];                                   // combine_weights
        out[off + (size_t)S * E * CAP] = 1.0f;                // dispatch_mask
    }
}

extern "C" void kernel_launch(void* const* d_in, const int* in_sizes, int n_in,
                              void* d_out, int out_size, void* d_ws, size_t ws_size,
                              hipStream_t stream) {
    const float* x = (const float*)d_in[0];      // [S, Dm] fp32
    const float* w = (const float*)d_in[1];      // [E, Dm] fp32
    float* out = (float*)d_out;

    // ws layout
    float* logits = (float*)d_ws;                // S*E floats
    float* gate = logits + (size_t)S * E;        // S floats
    int* idx = (int*)(gate + S);                 // S ints
    int* pos = idx + S;                          // S ints
    float* me_sum = (float*)(pos + S);           // E floats

    // zero the whole output (poisoned to 0xAA between timed replays) + me accum
    hipMemsetAsync(d_out, 0, (size_t)out_size * sizeof(float), stream);
    hipMemsetAsync(me_sum, 0, E * sizeof(float), stream);

    k_gemm<<<dim3(512), dim3(128), 0, stream>>>(x, w, logits);
    k_softmax<<<dim3(128), dim3(64), 0, stream>>>(logits, gate, idx, me_sum);
    k_scan<<<dim3(64), dim3(256), 0, stream>>>(
        idx, pos, me_sum, out + 1 + 2 * (size_t)S * E * CAP, out);
    k_scatter<<<dim3(32), dim3(256), 0, stream>>>(idx, pos, gate, out);
}